// Round 1
// baseline (147.150 us; speedup 1.0000x reference)
//
#include <hip/hip_runtime.h>
#include <hip/hip_bf16.h>

#define NF 40
#define NE 128
#define NA 128
#define NP 780        // NF*(NF-1)/2
#define NPT 784       // padded to 49*16
#define NMT 49        // m-tiles of 16 pairs
#define XS_LD 132     // x LDS row stride (floats): 132%32=4 -> conflict-free-ish, 16B aligned
#define WS_LD 136     // W LDS row stride (bf16):   136*2=272B, 272%128=16 -> 2-way max, 16B aligned

typedef short short8 __attribute__((ext_vector_type(8)));
typedef float floatx4 __attribute__((ext_vector_type(4)));

__device__ __forceinline__ unsigned short f2bf(float f) {
    union { float f; unsigned u; } v; v.f = f;
    unsigned r = v.u + 0x7FFFu + ((v.u >> 16) & 1u);   // RNE
    return (unsigned short)(r >> 16);
}

union WsAfm {
    unsigned short ws[NA][WS_LD];   // 34816 B, bf16 W
    float afmp[8][NE];              // 4096 B, reused after matmul phase
};

__global__ __launch_bounds__(256, 2)
void afm_fused_kernel(const float* __restrict__ xg,   // [B, F, E]
                      const float* __restrict__ wg,   // [A, E]
                      const float* __restrict__ wbg,  // [A]
                      const float* __restrict__ hg,   // [1, A]
                      const float* __restrict__ pwg,  // [1, E]
                      const float* __restrict__ pbg,  // [1]
                      float* __restrict__ out)        // [B]
{
    __shared__ float xs[NF][XS_LD];          // 21120 B fp32 x
    __shared__ WsAfm u;                      // 34816 B
    __shared__ float sc[NPT];                // 3136 B scores -> exp
    __shared__ int   ij[NPT];                // 3136 B packed (i<<8)|j
    __shared__ float red_max[4], red_sum[4], red_out[4];

    const int tid  = threadIdx.x;
    const int b    = blockIdx.x;
    const int lane = tid & 63;
    const int wid  = tid >> 6;
    const int col  = lane & 15;
    const int quad = (lane >> 4) & 3;

    // ---- stage x[b] (fp32) ----
    const float* xb = xg + (size_t)b * (NF * NE);
    for (int t = tid; t < NF * (NE / 4); t += 256) {
        int row = t >> 5, c = (t & 31) * 4;
        float4 v = *(const float4*)(xb + row * NE + c);
        *(float4*)&xs[row][c] = v;
    }
    // ---- stage W as bf16 ----
    for (int t = tid; t < NA * (NE / 4); t += 256) {
        int row = t >> 5, c = (t & 31) * 4;
        float4 v = *(const float4*)(wg + row * NE + c);
        u.ws[row][c + 0] = f2bf(v.x);
        u.ws[row][c + 1] = f2bf(v.y);
        u.ws[row][c + 2] = f2bf(v.z);
        u.ws[row][c + 3] = f2bf(v.w);
    }
    // ---- pair index table ----
    for (int p = tid; p < NPT; p += 256) {
        int v = 0;
        if (p < NP) {
            int i = 0, rem = p;
            while (rem >= (NF - 1 - i)) { rem -= (NF - 1 - i); ++i; }
            v = (i << 8) | (i + 1 + rem);
        }
        ij[p] = v;
    }
    // ---- per-lane epilogue constants (indexed by col) ----
    float wbr[8], hr[8];
#pragma unroll
    for (int n = 0; n < 8; ++n) {
        wbr[n] = wbg[n * 16 + col];
        hr[n]  = hg[n * 16 + col];
    }
    __syncthreads();

    // ---- W B-fragments into registers: B[n=col][k=quad*8+j] = W[a][e] ----
    short8 bfrag[8][4];
#pragma unroll
    for (int n = 0; n < 8; ++n)
#pragma unroll
        for (int k = 0; k < 4; ++k) {
            int row  = n * 16 + col;
            int koff = k * 32 + quad * 8;
            bfrag[n][k] = *(const short8*)&u.ws[row][koff];
        }

    // ---- main MFMA loop: S[p,a] = sum_e hp[p,e] * W[a,e] ----
    for (int mt = wid; mt < NMT; mt += 4) {
        const int p0 = mt * 16;
        const int v  = ij[p0 + col];          // A-row p0+col -> fields (i,j)
        const float* xip = &xs[(v >> 8) & 255][0];
        const float* xjp = &xs[v & 255][0];

        floatx4 acc[8];
#pragma unroll
        for (int n = 0; n < 8; ++n) acc[n] = (floatx4){0.f, 0.f, 0.f, 0.f};

#pragma unroll
        for (int k = 0; k < 4; ++k) {
            const int koff = k * 32 + quad * 8;
            float4 i0 = *(const float4*)(xip + koff);
            float4 i1 = *(const float4*)(xip + koff + 4);
            float4 j0 = *(const float4*)(xjp + koff);
            float4 j1 = *(const float4*)(xjp + koff + 4);
            short8 af;
            af[0] = (short)f2bf(i0.x * j0.x);
            af[1] = (short)f2bf(i0.y * j0.y);
            af[2] = (short)f2bf(i0.z * j0.z);
            af[3] = (short)f2bf(i0.w * j0.w);
            af[4] = (short)f2bf(i1.x * j1.x);
            af[5] = (short)f2bf(i1.y * j1.y);
            af[6] = (short)f2bf(i1.z * j1.z);
            af[7] = (short)f2bf(i1.w * j1.w);
#pragma unroll
            for (int n = 0; n < 8; ++n)
                acc[n] = __builtin_amdgcn_mfma_f32_16x16x32_bf16(af, bfrag[n][k], acc[n], 0, 0, 0);
        }

        // scores[p] = sum_a relu(S[p,a] + wb[a]) * h[a]   (h_b cancels in softmax)
        float ps[4] = {0.f, 0.f, 0.f, 0.f};
#pragma unroll
        for (int n = 0; n < 8; ++n) {
#pragma unroll
            for (int r = 0; r < 4; ++r) {
                float val = acc[n][r] + wbr[n];
                ps[r] += fmaxf(val, 0.f) * hr[n];
            }
        }
#pragma unroll
        for (int r = 0; r < 4; ++r) {
#pragma unroll
            for (int off = 1; off < 16; off <<= 1)
                ps[r] += __shfl_xor(ps[r], off);
        }
        if (col == 0) {
#pragma unroll
            for (int r = 0; r < 4; ++r) {
                int p = p0 + quad * 4 + r;
                if (p < NP) sc[p] = ps[r];
            }
        }
    }
    __syncthreads();

    // ---- softmax over 780 pairs (unnormalized exp; fold 1/sum at the end) ----
    float m = -1e30f;
    for (int p = tid; p < NP; p += 256) m = fmaxf(m, sc[p]);
#pragma unroll
    for (int off = 1; off < 64; off <<= 1) m = fmaxf(m, __shfl_xor(m, off));
    if (lane == 0) red_max[wid] = m;
    __syncthreads();
    const float M = fmaxf(fmaxf(red_max[0], red_max[1]), fmaxf(red_max[2], red_max[3]));

    float s = 0.f;
    for (int p = tid; p < NP; p += 256) {
        float e = __expf(sc[p] - M);
        sc[p] = e;
        s += e;
    }
#pragma unroll
    for (int off = 1; off < 64; off <<= 1) s += __shfl_xor(s, off);
    if (lane == 0) red_sum[wid] = s;
    __syncthreads();   // exp values visible; red_sum written

    // ---- afm[e] = sum_p exp_p * x[i_p,e] * x[j_p,e]  (fp32) ----
    const int q  = tid >> 5;            // 8 pair-chunks of <=98
    const int e0 = (tid & 31) * 4;      // 4 consecutive e per thread
    float a0 = 0.f, a1 = 0.f, a2 = 0.f, a3 = 0.f;
    const int pbeg = q * 98;
    const int pend = (pbeg + 98 < NP) ? (pbeg + 98) : NP;
    for (int p = pbeg; p < pend; ++p) {
        int vv = ij[p];
        float w = sc[p];
        float4 vi = *(const float4*)&xs[(vv >> 8) & 255][e0];
        float4 vj = *(const float4*)&xs[vv & 255][e0];
        a0 += w * vi.x * vj.x;
        a1 += w * vi.y * vj.y;
        a2 += w * vi.z * vj.z;
        a3 += w * vi.w * vj.w;
    }
    // ws (W bf16) is dead now; reuse as afm partial buffer
    *(float4*)&u.afmp[q][e0] = make_float4(a0, a1, a2, a3);
    __syncthreads();

    // ---- out[b] = (sum_e afm_un[e] * pw[e]) / sum_exp + p_b ----
    float vv = 0.f;
    if (tid < NE) {
        float a = 0.f;
#pragma unroll
        for (int qq = 0; qq < 8; ++qq) a += u.afmp[qq][tid];
        vv = a * pwg[tid];
    }
#pragma unroll
    for (int off = 1; off < 64; off <<= 1) vv += __shfl_xor(vv, off);
    if (lane == 0) red_out[wid] = vv;
    __syncthreads();
    if (tid == 0) {
        float S   = red_sum[0] + red_sum[1] + red_sum[2] + red_sum[3];
        float tot = red_out[0] + red_out[1] + red_out[2] + red_out[3];
        out[b] = tot / S + pbg[0];
    }
}

extern "C" void kernel_launch(void* const* d_in, const int* in_sizes, int n_in,
                              void* d_out, int out_size, void* d_ws, size_t ws_size,
                              hipStream_t stream) {
    const float* xg  = (const float*)d_in[0];  // x [B,F,E]
    const float* wg  = (const float*)d_in[1];  // attn_w_w [A,E]
    const float* wbg = (const float*)d_in[2];  // attn_w_b [A]
    const float* hg  = (const float*)d_in[3];  // attn_h_w [1,A]
    // d_in[4] = attn_h_b : constant shift, cancels in softmax
    const float* pwg = (const float*)d_in[5];  // attn_p_w [1,E]
    const float* pbg = (const float*)d_in[6];  // attn_p_b [1]
    const int B = in_sizes[0] / (NF * NE);
    afm_fused_kernel<<<B, 256, 0, stream>>>(xg, wg, wbg, hg, pwg, pbg, (float*)d_out);
}